// Round 12
// baseline (84.129 us; speedup 1.0000x reference)
//
#include <hip/hip_runtime.h>
#include <math.h>

static constexpr float kEps = 1e-5f;

// ---------- kernel 1: transpose x -> xt[pos][128 samples] (+ side packs) ----------
__global__ __launch_bounds__(256)
void xpose(const float* __restrict__ x, float* __restrict__ xt,
           const float* __restrict__ w1,
           const float* __restrict__ w2, const float* __restrict__ w3,
           const float* __restrict__ w4, const float* __restrict__ w5,
           const float* __restrict__ w6,
           const float* __restrict__ g1, const float* __restrict__ be1,
           float* __restrict__ w1p,
           float* __restrict__ w2t, float* __restrict__ w3t,
           float* __restrict__ w4t, float* __restrict__ w5t,
           float* __restrict__ w6t,
           float4* __restrict__ g1p, float4* __restrict__ be1p)
{
    const int bid = blockIdx.x, t = threadIdx.x;
    if (bid >= 784) {
        const int tid = (bid - 784) * 256 + t;
        const int nt  = 14 * 256;
        for (int i = tid; i < 11881 * 49; i += nt) {            // w1p [idx][7][8] padded
            const int idx = i / 49, kk = i - idx * 49;
            w1p[(size_t)idx * 56 + (kk / 7) * 8 + (kk % 7)] = w1[i];
        }
        for (int i = tid; i < 25 * 50 * 52; i += nt) {          // w2t [25][50][52]
            const int kk = i / (50 * 52), r = i % (50 * 52);
            const int oh = r / 52, ow = r % 52;
            w2t[i] = (ow < 50) ? w2[(oh * 50 + ow) * 25 + kk] : 0.f;
        }
        for (int i = tid; i < 9 * 2304; i += nt) {              // w3t [9][2304]
            const int kk = i / 2304, idx = i % 2304;
            w3t[i] = w3[idx * 9 + kk];
        }
        for (int i = tid; i < 9 * 22 * 24; i += nt) {           // w4t [9][22][24]
            const int kk = i / (22 * 24), r = i % (22 * 24);
            const int oh = r / 24, ow = r % 24;
            w4t[i] = (ow < 22) ? w4[(oh * 22 + ow) * 9 + kk] : 0.f;
        }
        for (int i = tid; i < 9 * 400; i += nt) {               // w5t [9][400]
            const int kk = i / 400, idx = i % 400;
            w5t[i] = w5[idx * 9 + kk];
        }
        for (int i = tid; i < 9 * 64; i += nt) {                // w6t [9][64]
            const int kk = i / 64, idx = i % 64;
            w6t[i] = w6[idx * 9 + kk];
        }
        for (int i = tid; i < 54 * 54; i += nt) {               // pool-window params
            const int ph = i / 54, pw = i - ph * 54;
            const int i00 = (2 * ph) * 109 + 2 * pw, i10 = i00 + 109;
            g1p[i]  = make_float4(g1[i00],  g1[i00 + 1],  g1[i10],  g1[i10 + 1]);
            be1p[i] = make_float4(be1[i00], be1[i00 + 1], be1[i10], be1[i10 + 1]);
        }
        return;
    }

    __shared__ float ls[64 * 133];
    const int pos0 = bid * 64;
    for (int i = t; i < 8192; i += 256) {
        const int s = i >> 6, j = i & 63;
        ls[j * 133 + s] = x[(size_t)s * 50176 + pos0 + j];
    }
    __syncthreads();
    for (int i = t; i < 8192; i += 256) {
        const int j = i >> 7, s = i & 127;
        xt[(size_t)(pos0 + j) * 128 + s] = ls[j * 133 + s];
    }
}

// ---------- kernel 2: conv1, sample-in-lane, 4x4 wave tile, FULL unroll ----------
// Wave: 4 output rows x 4 output cols x 64 samples. 13-row window fully unrolled:
// kh compile-time -> batched s_load weights from padded w1p[idx][7][8] (32B rows).
// Live x state = one 13-reg row; direct scatter stores (no LDS staging).
__global__ __launch_bounds__(256)
void conv1(const float* __restrict__ xt, const float* __restrict__ w1p,
           const float* __restrict__ bias, float* __restrict__ y,
           float* __restrict__ partial)
{
    __shared__ float redS[4][64], redQ[4][64];

    const int cg = blockIdx.x;    // 0..6   (16 cols each)
    const int rg = blockIdx.y;    // 0..27  (4 rows each)
    const int grp = blockIdx.z;   // 0..1   (64 samples each)
    const int t = threadIdx.x, w = t >> 6, lane = t & 63;
    const int smp = grp * 64 + lane;
    const int or0 = rg * 4;
    const int ow0 = cg * 16 + w * 4;
    const int ih0 = or0 * 2, ic0 = ow0 * 2;

    float acc[4][4];
    int idxo[4][4];
    #pragma unroll
    for (int a = 0; a < 4; ++a) {
        #pragma unroll
        for (int oc = 0; oc < 4; ++oc) {
            const int orow = min(or0 + a, 108), ow = min(ow0 + oc, 108);
            idxo[a][oc] = __builtin_amdgcn_readfirstlane(orow * 109 + ow);
            acc[a][oc] = bias[idxo[a][oc]];
        }
    }

    #pragma unroll
    for (int r = 0; r < 13; ++r) {
        float xr[13];
        const int rr = min(ih0 + r, 223);
        #pragma unroll
        for (int c = 0; c < 13; ++c)
            xr[c] = xt[((size_t)rr * 224 + min(ic0 + c, 223)) * 128 + smp];
        #pragma unroll
        for (int a = 0; a < 4; ++a) {
            const int kh = r - 2 * a;          // compile-time (full unroll)
            if (kh >= 0 && kh < 7) {
                #pragma unroll
                for (int oc = 0; oc < 4; ++oc) {
                    const float* __restrict__ wr = w1p + (size_t)idxo[a][oc] * 56 + kh * 8;
                    #pragma unroll
                    for (int kw = 0; kw < 7; ++kw)
                        acc[a][oc] = fmaf(xr[2 * oc + kw], wr[kw], acc[a][oc]);
                }
            }
        }
    }

    float lsum = 0.f, lsq = 0.f;
    #pragma unroll
    for (int a = 0; a < 4; ++a) {
        #pragma unroll
        for (int oc = 0; oc < 4; ++oc) {
            const int orow = or0 + a, ow = ow0 + oc;
            if (orow < 109 && ow < 109) {
                const float v = fmaxf(acc[a][oc], 0.f);
                y[((size_t)smp * 109 + orow) * 112 + ow] = v;
                lsum += v; lsq = fmaf(v, v, lsq);
            }
        }
    }
    redS[w][lane] = lsum; redQ[w][lane] = lsq;
    __syncthreads();
    if (w == 0) {
        const float s = redS[0][lane] + redS[1][lane] + redS[2][lane] + redS[3][lane];
        const float q = redQ[0][lane] + redQ[1][lane] + redQ[2][lane] + redQ[3][lane];
        *(float2*)(partial + ((size_t)smp * 196 + rg * 7 + cg) * 2) = make_float2(s, q);
    }
}

// ---------- block stats for 16 waves: one barrier, all threads get result ----------
__device__ inline float2 bstats(float ls, float lq, float invN, float (*red)[2], int t)
{
    #pragma unroll
    for (int off = 32; off > 0; off >>= 1) {
        ls += __shfl_down(ls, off, 64);
        lq += __shfl_down(lq, off, 64);
    }
    if ((t & 63) == 0) { red[t >> 6][0] = ls; red[t >> 6][1] = lq; }
    __syncthreads();
    float s = 0.f, q = 0.f;
    #pragma unroll
    for (int w = 0; w < 16; ++w) { s += red[w][0]; q += red[w][1]; }
    const float m = s * invN;
    return make_float2(m, rsqrtf(q * invN - m * m + kEps));
}

// ---------- kernel 3: everything after conv1, one 1024-thread block per sample ----------
__global__ __launch_bounds__(1024)
void tail(const float* __restrict__ y1, const float* __restrict__ partial,
          const float4* __restrict__ g1p, const float4* __restrict__ be1p,
          const float* __restrict__ w2t, const float* __restrict__ b2,
          const float* __restrict__ g2, const float* __restrict__ be2,
          const float* __restrict__ w3t, const float* __restrict__ b3,
          const float* __restrict__ g3, const float* __restrict__ be3,
          const float* __restrict__ w4t, const float* __restrict__ b4,
          const float* __restrict__ g4, const float* __restrict__ be4,
          const float* __restrict__ w5t, const float* __restrict__ b5,
          const float* __restrict__ g5, const float* __restrict__ be5,
          const float* __restrict__ w6t, const float* __restrict__ b6,
          const float* __restrict__ g6, const float* __restrict__ be6,
          const float* __restrict__ fcw, const float* __restrict__ fcb,
          float* __restrict__ out)
{
    __shared__ __align__(16) float xs54[54 * 54 + 8];
    __shared__ __align__(16) float y50[50 * 52];
    __shared__ __align__(16) float y48[48 * 48];
    __shared__ __align__(16) float xs24[24 * 24 + 8];
    __shared__ __align__(16) float y22[22 * 24];
    __shared__ __align__(16) float y20[20 * 20];
    __shared__ __align__(16) float xs10[100];
    __shared__ float y8[64], h[64];
    __shared__ float red[16][2];

    const int b = blockIdx.x, t = threadIdx.x;
    const int lane = t & 63;

    // ---- LN1 stats from 196 per-tile partials ----
    float s0 = 0.f, q0 = 0.f;
    if (t < 196) {
        const float2 p = *(const float2*)(partial + ((size_t)b * 196 + t) * 2);
        s0 = p.x; q0 = p.y;
    }
    const float2 st1 = bstats(s0, q0, 1.f / 11881.f, red, t);
    const float m1 = st1.x, r1 = st1.y;

    // ---- LN1 + 2x2 pool -> xs54 ----
    const float* yb = y1 + (size_t)b * 109 * 112;
    #pragma unroll
    for (int it = 0; it < 3; ++it) {
        const int idx = t + it * 1024;
        if (idx < 54 * 54) {
            const int ph = idx / 54, pw = idx - ph * 54;
            const int r0 = 2 * ph, c0 = 2 * pw;
            const float2 u0 = *(const float2*)(yb + r0 * 112 + c0);
            const float2 u1 = *(const float2*)(yb + (r0 + 1) * 112 + c0);
            const float4 g = g1p[idx], be = be1p[idx];
            const float v0 = (u0.x - m1) * r1 * g.x + be.x;
            const float v1 = (u0.y - m1) * r1 * g.y + be.y;
            const float v2 = (u1.x - m1) * r1 * g.z + be.z;
            const float v3 = (u1.y - m1) * r1 * g.w + be.w;
            xs54[ph * 54 + pw] = fmaxf(fmaxf(v0, v1), fmaxf(v2, v3));
        }
    }
    __syncthreads();

    // ---- L2: 54 -> conv5 -> relu -> y50 ----
    float ls = 0.f, lq = 0.f;
    if (t < 650) {
        const int oh = t / 13, qc = t - oh * 13;
        const int ow0 = qc * 4;
        float acc[4];
        #pragma unroll
        for (int o = 0; o < 4; ++o) acc[o] = (ow0 + o < 50) ? b2[oh * 50 + ow0 + o] : 0.f;
        #pragma unroll
        for (int kh = 0; kh < 5; ++kh) {
            const float* xp = xs54 + (oh + kh) * 54 + ow0;
            float a[8];
            #pragma unroll
            for (int i = 0; i < 4; ++i) {
                const float2 v = *(const float2*)(xp + 2 * i);
                a[2 * i] = v.x; a[2 * i + 1] = v.y;
            }
            #pragma unroll
            for (int kw = 0; kw < 5; ++kw) {
                const float4 w4 = *(const float4*)(w2t + ((size_t)(kh * 5 + kw) * 50 + oh) * 52 + ow0);
                acc[0] = fmaf(a[kw    ], w4.x, acc[0]);
                acc[1] = fmaf(a[kw + 1], w4.y, acc[1]);
                acc[2] = fmaf(a[kw + 2], w4.z, acc[2]);
                acc[3] = fmaf(a[kw + 3], w4.w, acc[3]);
            }
        }
        #pragma unroll
        for (int o = 0; o < 4; ++o) {
            const float v = fmaxf(acc[o], 0.f);
            y50[oh * 52 + ow0 + o] = v;
            if (ow0 + o < 50) { ls += v; lq = fmaf(v, v, lq); }
        }
    }
    const float2 s2 = bstats(ls, lq, 1.f / 2500.f, red, t);

    // ---- LN2 in place ----
    #pragma unroll
    for (int it = 0; it < 3; ++it) {
        const int idx = t + it * 1024;
        if (idx < 2500) {
            const int oh = idx / 50, ow = idx - oh * 50;
            const int p = oh * 52 + ow;
            y50[p] = (y50[p] - s2.x) * s2.y * g2[idx] + be2[idx];
        }
    }
    __syncthreads();

    // ---- L3: 50 -> conv3 -> relu -> y48 ----
    ls = 0.f; lq = 0.f;
    if (t < 576) {
        const int oh = t / 12, qc = t - oh * 12;
        const int ow0 = qc * 4;
        float acc[4];
        #pragma unroll
        for (int o = 0; o < 4; ++o) acc[o] = b3[oh * 48 + ow0 + o];
        #pragma unroll
        for (int kh = 0; kh < 3; ++kh) {
            const float* xp = y50 + (oh + kh) * 52 + ow0;
            float a[6];
            #pragma unroll
            for (int i = 0; i < 3; ++i) {
                const float2 v = *(const float2*)(xp + 2 * i);
                a[2 * i] = v.x; a[2 * i + 1] = v.y;
            }
            #pragma unroll
            for (int kw = 0; kw < 3; ++kw) {
                const float4 w4 = *(const float4*)(w3t + (size_t)(kh * 3 + kw) * 2304 + oh * 48 + ow0);
                acc[0] = fmaf(a[kw    ], w4.x, acc[0]);
                acc[1] = fmaf(a[kw + 1], w4.y, acc[1]);
                acc[2] = fmaf(a[kw + 2], w4.z, acc[2]);
                acc[3] = fmaf(a[kw + 3], w4.w, acc[3]);
            }
        }
        float4 st;
        #pragma unroll
        for (int o = 0; o < 4; ++o) {
            const float v = fmaxf(acc[o], 0.f);
            (&st.x)[o] = v; ls += v; lq = fmaf(v, v, lq);
        }
        *(float4*)(y48 + oh * 48 + ow0) = st;
    }
    const float2 s3 = bstats(ls, lq, 1.f / 2304.f, red, t);

    // ---- LN3 + pool -> xs24 ----
    if (t < 576) {
        const int ph = t / 24, pw = t - ph * 24;
        const int r0 = 2 * ph, c0 = 2 * pw;
        const float2 u0 = *(const float2*)(y48 + r0 * 48 + c0);
        const float2 u1 = *(const float2*)(y48 + (r0 + 1) * 48 + c0);
        const int i00 = r0 * 48 + c0, i10 = i00 + 48;
        const float v0 = (u0.x - s3.x) * s3.y * g3[i00]     + be3[i00];
        const float v1 = (u0.y - s3.x) * s3.y * g3[i00 + 1] + be3[i00 + 1];
        const float v2 = (u1.x - s3.x) * s3.y * g3[i10]     + be3[i10];
        const float v3 = (u1.y - s3.x) * s3.y * g3[i10 + 1] + be3[i10 + 1];
        xs24[ph * 24 + pw] = fmaxf(fmaxf(v0, v1), fmaxf(v2, v3));
    }
    __syncthreads();

    // ---- L4: 24 -> conv3 -> relu -> y22 ----
    ls = 0.f; lq = 0.f;
    if (t < 132) {
        const int oh = t / 6, qc = t - oh * 6;
        const int ow0 = qc * 4;
        float acc[4];
        #pragma unroll
        for (int o = 0; o < 4; ++o) acc[o] = (ow0 + o < 22) ? b4[oh * 22 + ow0 + o] : 0.f;
        #pragma unroll
        for (int kh = 0; kh < 3; ++kh) {
            const float* xp = xs24 + (oh + kh) * 24 + ow0;
            float a[6];
            #pragma unroll
            for (int i = 0; i < 3; ++i) {
                const float2 v = *(const float2*)(xp + 2 * i);
                a[2 * i] = v.x; a[2 * i + 1] = v.y;
            }
            #pragma unroll
            for (int kw = 0; kw < 3; ++kw) {
                const float4 w4 = *(const float4*)(w4t + ((size_t)(kh * 3 + kw) * 22 + oh) * 24 + ow0);
                acc[0] = fmaf(a[kw    ], w4.x, acc[0]);
                acc[1] = fmaf(a[kw + 1], w4.y, acc[1]);
                acc[2] = fmaf(a[kw + 2], w4.z, acc[2]);
                acc[3] = fmaf(a[kw + 3], w4.w, acc[3]);
            }
        }
        #pragma unroll
        for (int o = 0; o < 4; ++o) {
            const float v = fmaxf(acc[o], 0.f);
            y22[oh * 24 + ow0 + o] = v;
            if (ow0 + o < 22) { ls += v; lq = fmaf(v, v, lq); }
        }
    }
    const float2 s4 = bstats(ls, lq, 1.f / 484.f, red, t);

    // ---- LN4 in place ----
    if (t < 484) {
        const int oh = t / 22, ow = t - oh * 22;
        const int p = oh * 24 + ow;
        y22[p] = (y22[p] - s4.x) * s4.y * g4[t] + be4[t];
    }
    __syncthreads();

    // ---- L5: 22 -> conv3 -> relu -> y20 ----
    ls = 0.f; lq = 0.f;
    if (t < 100) {
        const int oh = t / 5, qc = t - oh * 5;
        const int ow0 = qc * 4;
        float acc[4];
        #pragma unroll
        for (int o = 0; o < 4; ++o) acc[o] = b5[oh * 20 + ow0 + o];
        #pragma unroll
        for (int kh = 0; kh < 3; ++kh) {
            const float* xp = y22 + (oh + kh) * 24 + ow0;
            float a[6];
            #pragma unroll
            for (int i = 0; i < 3; ++i) {
                const float2 v = *(const float2*)(xp + 2 * i);
                a[2 * i] = v.x; a[2 * i + 1] = v.y;
            }
            #pragma unroll
            for (int kw = 0; kw < 3; ++kw) {
                const float4 w4 = *(const float4*)(w5t + (size_t)(kh * 3 + kw) * 400 + oh * 20 + ow0);
                acc[0] = fmaf(a[kw    ], w4.x, acc[0]);
                acc[1] = fmaf(a[kw + 1], w4.y, acc[1]);
                acc[2] = fmaf(a[kw + 2], w4.z, acc[2]);
                acc[3] = fmaf(a[kw + 3], w4.w, acc[3]);
            }
        }
        #pragma unroll
        for (int o = 0; o < 4; ++o) {
            const float v = fmaxf(acc[o], 0.f);
            y20[oh * 20 + ow0 + o] = v;
            ls += v; lq = fmaf(v, v, lq);
        }
    }
    const float2 s5 = bstats(ls, lq, 1.f / 400.f, red, t);

    // ---- LN5 + pool -> xs10 ----
    if (t < 100) {
        const int ph = t / 10, pw = t - ph * 10;
        const int r0 = 2 * ph, c0 = 2 * pw;
        const float2 u0 = *(const float2*)(y20 + r0 * 20 + c0);
        const float2 u1 = *(const float2*)(y20 + (r0 + 1) * 20 + c0);
        const int i00 = r0 * 20 + c0, i10 = i00 + 20;
        const float v0 = (u0.x - s5.x) * s5.y * g5[i00]     + be5[i00];
        const float v1 = (u0.y - s5.x) * s5.y * g5[i00 + 1] + be5[i00 + 1];
        const float v2 = (u1.x - s5.x) * s5.y * g5[i10]     + be5[i10];
        const float v3 = (u1.y - s5.x) * s5.y * g5[i10 + 1] + be5[i10 + 1];
        xs10[ph * 10 + pw] = fmaxf(fmaxf(v0, v1), fmaxf(v2, v3));
    }
    __syncthreads();

    // ---- L6: 10 -> conv3 -> relu -> y8 ----
    ls = 0.f; lq = 0.f;
    if (t < 16) {
        const int oh = t / 2, qc = t - oh * 2;
        const int ow0 = qc * 4;
        float acc[4];
        #pragma unroll
        for (int o = 0; o < 4; ++o) acc[o] = b6[oh * 8 + ow0 + o];
        #pragma unroll
        for (int kh = 0; kh < 3; ++kh) {
            const float* xp = xs10 + (oh + kh) * 10 + ow0;
            float a[6];
            #pragma unroll
            for (int i = 0; i < 3; ++i) {
                const float2 v = *(const float2*)(xp + 2 * i);
                a[2 * i] = v.x; a[2 * i + 1] = v.y;
            }
            #pragma unroll
            for (int kw = 0; kw < 3; ++kw) {
                const float4 w4 = *(const float4*)(w6t + (size_t)(kh * 3 + kw) * 64 + oh * 8 + ow0);
                acc[0] = fmaf(a[kw    ], w4.x, acc[0]);
                acc[1] = fmaf(a[kw + 1], w4.y, acc[1]);
                acc[2] = fmaf(a[kw + 2], w4.z, acc[2]);
                acc[3] = fmaf(a[kw + 3], w4.w, acc[3]);
            }
        }
        #pragma unroll
        for (int o = 0; o < 4; ++o) {
            const float v = fmaxf(acc[o], 0.f);
            y8[oh * 8 + ow0 + o] = v;
            ls += v; lq = fmaf(v, v, lq);
        }
    }
    const float2 s6 = bstats(ls, lq, 1.f / 64.f, red, t);

    // ---- LN6 -> h ----
    if (t < 64) h[t] = (y8[t] - s6.x) * s6.y * g6[t] + be6[t];
    __syncthreads();

    // ---- FC 64 -> 1000 (1 task/thread) + softmax ----
    float lj = -INFINITY;
    if (t < 1000) {
        const float4* wr = (const float4*)(fcw + (size_t)t * 64);
        float acc = fcb[t];
        #pragma unroll
        for (int k = 0; k < 16; ++k) {
            const float4 w4 = wr[k];
            acc = fmaf(h[4 * k], w4.x,
                  fmaf(h[4 * k + 1], w4.y,
                  fmaf(h[4 * k + 2], w4.z,
                  fmaf(h[4 * k + 3], w4.w, acc))));
        }
        lj = acc;
    }
    float mx = lj;
    #pragma unroll
    for (int off = 32; off > 0; off >>= 1) mx = fmaxf(mx, __shfl_down(mx, off, 64));
    if (lane == 0) red[t >> 6][0] = mx;
    __syncthreads();
    float gmax = red[0][0];
    #pragma unroll
    for (int w = 1; w < 16; ++w) gmax = fmaxf(gmax, red[w][0]);

    const float e = (t < 1000) ? __expf(lj - gmax) : 0.f;
    float ssum = e;
    #pragma unroll
    for (int off = 32; off > 0; off >>= 1) ssum += __shfl_down(ssum, off, 64);
    if (lane == 0) red[t >> 6][1] = ssum;
    __syncthreads();
    float tot = 0.f;
    #pragma unroll
    for (int w = 0; w < 16; ++w) tot += red[w][1];
    if (t < 1000) out[(size_t)b * 1000 + t] = e / tot;
}

extern "C" void kernel_launch(void* const* d_in, const int* in_sizes, int n_in,
                              void* d_out, int out_size, void* d_ws, size_t ws_size,
                              hipStream_t stream) {
    const float* x   = (const float*)d_in[0];
    const float* w1  = (const float*)d_in[1];
    const float* b1  = (const float*)d_in[2];
    const float* g1  = (const float*)d_in[3];
    const float* be1 = (const float*)d_in[4];
    const float* w2  = (const float*)d_in[5];
    const float* b2  = (const float*)d_in[6];
    const float* g2  = (const float*)d_in[7];
    const float* be2 = (const float*)d_in[8];
    const float* w3  = (const float*)d_in[9];
    const float* b3  = (const float*)d_in[10];
    const float* g3  = (const float*)d_in[11];
    const float* be3 = (const float*)d_in[12];
    const float* w4  = (const float*)d_in[13];
    const float* b4  = (const float*)d_in[14];
    const float* g4  = (const float*)d_in[15];
    const float* be4 = (const float*)d_in[16];
    const float* w5  = (const float*)d_in[17];
    const float* b5  = (const float*)d_in[18];
    const float* g5  = (const float*)d_in[19];
    const float* be5 = (const float*)d_in[20];
    const float* w6  = (const float*)d_in[21];
    const float* b6  = (const float*)d_in[22];
    const float* g6  = (const float*)d_in[23];
    const float* be6 = (const float*)d_in[24];
    const float* fcw = (const float*)d_in[25];
    const float* fcb = (const float*)d_in[26];

    float* xt   = (float*)d_ws;                 // 50176*128  = 6,422,528
    float* y1p  = xt   + 6422528;               // 128*109*112= 1,562,624
    float* w1pp = y1p  + 1562624;               // 11881*56   =   665,336
    float* w2t  = w1pp + 665336;                // 25*50*52   =    65,000
    float* w3t  = w2t  + 65000;                 // 9*2304     =    20,736
    float* w4t  = w3t  + 20736;                 // 9*22*24    =     4,752
    float* w5t  = w4t  + 4752;                  // 9*400      =     3,600
    float* w6t  = w5t  + 3600;                  // 9*64       =       576
    float* part = w6t  + 576;                   // 128*196*2  =    50,176
    float* g1pp = part + 50176;                 // 2916*4     =    11,664
    float* be1pp= g1pp + 11664;                 // 2916*4     =    11,664

    xpose<<<798, 256, 0, stream>>>(x, xt, w1,
                                   w2, w3, w4, w5, w6, g1, be1,
                                   w1pp, w2t, w3t, w4t, w5t, w6t,
                                   (float4*)g1pp, (float4*)be1pp);

    conv1<<<dim3(7, 28, 2), 256, 0, stream>>>(xt, w1pp, b1, y1p, part);

    tail<<<128, 1024, 0, stream>>>(y1p, part,
                                   (const float4*)g1pp, (const float4*)be1pp,
                                   w2t, b2, g2, be2,
                                   w3t, b3, g3, be3,
                                   w4t, b4, g4, be4,
                                   w5t, b5, g5, be5,
                                   w6t, b6, g6, be6,
                                   fcw, fcb, (float*)d_out);
}

// Round 13
// 59.600 us; speedup vs baseline: 1.4115x; 1.4115x over previous
//
#include <hip/hip_runtime.h>
#include <math.h>

static constexpr float kEps = 1e-5f;

// ---------- kernel 1: transpose x -> xt[pos][128 samples] (+ side packs) ----------
// Blocks 0..783: 64pos x 128smp LDS transpose tiles.
// Blocks 784..895 (112 blocks = 28672 threads): weight repacks -> ~21 iters max
// (R12 used 14 blocks -> 162 serial-latency iters = 50us tail; this fixes that).
__global__ __launch_bounds__(256)
void xpose(const float* __restrict__ x, float* __restrict__ xt,
           const float* __restrict__ w1,
           const float* __restrict__ w2, const float* __restrict__ w3,
           const float* __restrict__ w4, const float* __restrict__ w5,
           const float* __restrict__ w6,
           const float* __restrict__ g1, const float* __restrict__ be1,
           float* __restrict__ w1p,
           float* __restrict__ w2t, float* __restrict__ w3t,
           float* __restrict__ w4t, float* __restrict__ w5t,
           float* __restrict__ w6t,
           float4* __restrict__ g1p, float4* __restrict__ be1p)
{
    const int bid = blockIdx.x, t = threadIdx.x;
    if (bid >= 784) {
        const int tid = (bid - 784) * 256 + t;
        const int nt  = 112 * 256;
        #pragma unroll 4
        for (int i = tid; i < 11881 * 49; i += nt) {            // w1p [idx][7][8] padded
            const int idx = i / 49, kk = i - idx * 49;
            w1p[(size_t)idx * 56 + (kk / 7) * 8 + (kk % 7)] = w1[i];
        }
        #pragma unroll 2
        for (int i = tid; i < 25 * 50 * 52; i += nt) {          // w2t [25][50][52]
            const int kk = i / (50 * 52), r = i % (50 * 52);
            const int oh = r / 52, ow = r % 52;
            w2t[i] = (ow < 50) ? w2[(oh * 50 + ow) * 25 + kk] : 0.f;
        }
        for (int i = tid; i < 9 * 2304; i += nt) {              // w3t [9][2304]
            const int kk = i / 2304, idx = i % 2304;
            w3t[i] = w3[idx * 9 + kk];
        }
        for (int i = tid; i < 9 * 22 * 24; i += nt) {           // w4t [9][22][24]
            const int kk = i / (22 * 24), r = i % (22 * 24);
            const int oh = r / 24, ow = r % 24;
            w4t[i] = (ow < 22) ? w4[(oh * 22 + ow) * 9 + kk] : 0.f;
        }
        for (int i = tid; i < 9 * 400; i += nt) {               // w5t [9][400]
            const int kk = i / 400, idx = i % 400;
            w5t[i] = w5[idx * 9 + kk];
        }
        for (int i = tid; i < 9 * 64; i += nt) {                // w6t [9][64]
            const int kk = i / 64, idx = i % 64;
            w6t[i] = w6[idx * 9 + kk];
        }
        for (int i = tid; i < 54 * 54; i += nt) {               // pool-window params
            const int ph = i / 54, pw = i - ph * 54;
            const int i00 = (2 * ph) * 109 + 2 * pw, i10 = i00 + 109;
            g1p[i]  = make_float4(g1[i00],  g1[i00 + 1],  g1[i10],  g1[i10 + 1]);
            be1p[i] = make_float4(be1[i00], be1[i00 + 1], be1[i10], be1[i10 + 1]);
        }
        return;
    }

    __shared__ float ls[64 * 133];
    const int pos0 = bid * 64;
    for (int i = t; i < 8192; i += 256) {
        const int s = i >> 6, j = i & 63;
        ls[j * 133 + s] = x[(size_t)s * 50176 + pos0 + j];
    }
    __syncthreads();
    for (int i = t; i < 8192; i += 256) {
        const int j = i >> 7, s = i & 127;
        xt[(size_t)(pos0 + j) * 128 + s] = ls[j * 133 + s];
    }
}

// ---------- kernel 2: conv1, sample-in-lane, 4x4 wave tile, FULL unroll ----------
// (unchanged from R12 -- it dropped below the 40us profiler floor there)
__global__ __launch_bounds__(256)
void conv1(const float* __restrict__ xt, const float* __restrict__ w1p,
           const float* __restrict__ bias, float* __restrict__ y,
           float* __restrict__ partial)
{
    __shared__ float redS[4][64], redQ[4][64];

    const int cg = blockIdx.x;    // 0..6   (16 cols each)
    const int rg = blockIdx.y;    // 0..27  (4 rows each)
    const int grp = blockIdx.z;   // 0..1   (64 samples each)
    const int t = threadIdx.x, w = t >> 6, lane = t & 63;
    const int smp = grp * 64 + lane;
    const int or0 = rg * 4;
    const int ow0 = cg * 16 + w * 4;
    const int ih0 = or0 * 2, ic0 = ow0 * 2;

    float acc[4][4];
    int idxo[4][4];
    #pragma unroll
    for (int a = 0; a < 4; ++a) {
        #pragma unroll
        for (int oc = 0; oc < 4; ++oc) {
            const int orow = min(or0 + a, 108), ow = min(ow0 + oc, 108);
            idxo[a][oc] = __builtin_amdgcn_readfirstlane(orow * 109 + ow);
            acc[a][oc] = bias[idxo[a][oc]];
        }
    }

    #pragma unroll
    for (int r = 0; r < 13; ++r) {
        float xr[13];
        const int rr = min(ih0 + r, 223);
        #pragma unroll
        for (int c = 0; c < 13; ++c)
            xr[c] = xt[((size_t)rr * 224 + min(ic0 + c, 223)) * 128 + smp];
        #pragma unroll
        for (int a = 0; a < 4; ++a) {
            const int kh = r - 2 * a;          // compile-time (full unroll)
            if (kh >= 0 && kh < 7) {
                #pragma unroll
                for (int oc = 0; oc < 4; ++oc) {
                    const float* __restrict__ wr = w1p + (size_t)idxo[a][oc] * 56 + kh * 8;
                    #pragma unroll
                    for (int kw = 0; kw < 7; ++kw)
                        acc[a][oc] = fmaf(xr[2 * oc + kw], wr[kw], acc[a][oc]);
                }
            }
        }
    }

    float lsum = 0.f, lsq = 0.f;
    #pragma unroll
    for (int a = 0; a < 4; ++a) {
        #pragma unroll
        for (int oc = 0; oc < 4; ++oc) {
            const int orow = or0 + a, ow = ow0 + oc;
            if (orow < 109 && ow < 109) {
                const float v = fmaxf(acc[a][oc], 0.f);
                y[((size_t)smp * 109 + orow) * 112 + ow] = v;
                lsum += v; lsq = fmaf(v, v, lsq);
            }
        }
    }
    redS[w][lane] = lsum; redQ[w][lane] = lsq;
    __syncthreads();
    if (w == 0) {
        const float s = redS[0][lane] + redS[1][lane] + redS[2][lane] + redS[3][lane];
        const float q = redQ[0][lane] + redQ[1][lane] + redQ[2][lane] + redQ[3][lane];
        *(float2*)(partial + ((size_t)smp * 196 + rg * 7 + cg) * 2) = make_float2(s, q);
    }
}

// ---------- block stats for 16 waves: one barrier, all threads get result ----------
__device__ inline float2 bstats(float ls, float lq, float invN, float (*red)[2], int t)
{
    #pragma unroll
    for (int off = 32; off > 0; off >>= 1) {
        ls += __shfl_down(ls, off, 64);
        lq += __shfl_down(lq, off, 64);
    }
    if ((t & 63) == 0) { red[t >> 6][0] = ls; red[t >> 6][1] = lq; }
    __syncthreads();
    float s = 0.f, q = 0.f;
    #pragma unroll
    for (int w = 0; w < 16; ++w) { s += red[w][0]; q += red[w][1]; }
    const float m = s * invN;
    return make_float2(m, rsqrtf(q * invN - m * m + kEps));
}

// ---------- kernel 3: everything after conv1, one 1024-thread block per sample ----------
__global__ __launch_bounds__(1024)
void tail(const float* __restrict__ y1, const float* __restrict__ partial,
          const float4* __restrict__ g1p, const float4* __restrict__ be1p,
          const float* __restrict__ w2t, const float* __restrict__ b2,
          const float* __restrict__ g2, const float* __restrict__ be2,
          const float* __restrict__ w3t, const float* __restrict__ b3,
          const float* __restrict__ g3, const float* __restrict__ be3,
          const float* __restrict__ w4t, const float* __restrict__ b4,
          const float* __restrict__ g4, const float* __restrict__ be4,
          const float* __restrict__ w5t, const float* __restrict__ b5,
          const float* __restrict__ g5, const float* __restrict__ be5,
          const float* __restrict__ w6t, const float* __restrict__ b6,
          const float* __restrict__ g6, const float* __restrict__ be6,
          const float* __restrict__ fcw, const float* __restrict__ fcb,
          float* __restrict__ out)
{
    __shared__ __align__(16) float xs54[54 * 54 + 8];
    __shared__ __align__(16) float y50[50 * 52];
    __shared__ __align__(16) float y48[48 * 48];
    __shared__ __align__(16) float xs24[24 * 24 + 8];
    __shared__ __align__(16) float y22[22 * 24];
    __shared__ __align__(16) float y20[20 * 20];
    __shared__ __align__(16) float xs10[100];
    __shared__ float y8[64], h[64];
    __shared__ float red[16][2];

    const int b = blockIdx.x, t = threadIdx.x;
    const int lane = t & 63;

    // ---- LN1 stats from 196 per-tile partials ----
    float s0 = 0.f, q0 = 0.f;
    if (t < 196) {
        const float2 p = *(const float2*)(partial + ((size_t)b * 196 + t) * 2);
        s0 = p.x; q0 = p.y;
    }
    const float2 st1 = bstats(s0, q0, 1.f / 11881.f, red, t);
    const float m1 = st1.x, r1 = st1.y;

    // ---- LN1 + 2x2 pool -> xs54 ----
    const float* yb = y1 + (size_t)b * 109 * 112;
    #pragma unroll
    for (int it = 0; it < 3; ++it) {
        const int idx = t + it * 1024;
        if (idx < 54 * 54) {
            const int ph = idx / 54, pw = idx - ph * 54;
            const int r0 = 2 * ph, c0 = 2 * pw;
            const float2 u0 = *(const float2*)(yb + r0 * 112 + c0);
            const float2 u1 = *(const float2*)(yb + (r0 + 1) * 112 + c0);
            const float4 g = g1p[idx], be = be1p[idx];
            const float v0 = (u0.x - m1) * r1 * g.x + be.x;
            const float v1 = (u0.y - m1) * r1 * g.y + be.y;
            const float v2 = (u1.x - m1) * r1 * g.z + be.z;
            const float v3 = (u1.y - m1) * r1 * g.w + be.w;
            xs54[ph * 54 + pw] = fmaxf(fmaxf(v0, v1), fmaxf(v2, v3));
        }
    }
    __syncthreads();

    // ---- L2: 54 -> conv5 -> relu -> y50 ----
    float ls = 0.f, lq = 0.f;
    if (t < 650) {
        const int oh = t / 13, qc = t - oh * 13;
        const int ow0 = qc * 4;
        float acc[4];
        #pragma unroll
        for (int o = 0; o < 4; ++o) acc[o] = (ow0 + o < 50) ? b2[oh * 50 + ow0 + o] : 0.f;
        #pragma unroll
        for (int kh = 0; kh < 5; ++kh) {
            const float* xp = xs54 + (oh + kh) * 54 + ow0;
            float a[8];
            #pragma unroll
            for (int i = 0; i < 4; ++i) {
                const float2 v = *(const float2*)(xp + 2 * i);
                a[2 * i] = v.x; a[2 * i + 1] = v.y;
            }
            #pragma unroll
            for (int kw = 0; kw < 5; ++kw) {
                const float4 w4 = *(const float4*)(w2t + ((size_t)(kh * 5 + kw) * 50 + oh) * 52 + ow0);
                acc[0] = fmaf(a[kw    ], w4.x, acc[0]);
                acc[1] = fmaf(a[kw + 1], w4.y, acc[1]);
                acc[2] = fmaf(a[kw + 2], w4.z, acc[2]);
                acc[3] = fmaf(a[kw + 3], w4.w, acc[3]);
            }
        }
        #pragma unroll
        for (int o = 0; o < 4; ++o) {
            const float v = fmaxf(acc[o], 0.f);
            y50[oh * 52 + ow0 + o] = v;
            if (ow0 + o < 50) { ls += v; lq = fmaf(v, v, lq); }
        }
    }
    const float2 s2 = bstats(ls, lq, 1.f / 2500.f, red, t);

    // ---- LN2 in place ----
    #pragma unroll
    for (int it = 0; it < 3; ++it) {
        const int idx = t + it * 1024;
        if (idx < 2500) {
            const int oh = idx / 50, ow = idx - oh * 50;
            const int p = oh * 52 + ow;
            y50[p] = (y50[p] - s2.x) * s2.y * g2[idx] + be2[idx];
        }
    }
    __syncthreads();

    // ---- L3: 50 -> conv3 -> relu -> y48 ----
    ls = 0.f; lq = 0.f;
    if (t < 576) {
        const int oh = t / 12, qc = t - oh * 12;
        const int ow0 = qc * 4;
        float acc[4];
        #pragma unroll
        for (int o = 0; o < 4; ++o) acc[o] = b3[oh * 48 + ow0 + o];
        #pragma unroll
        for (int kh = 0; kh < 3; ++kh) {
            const float* xp = y50 + (oh + kh) * 52 + ow0;
            float a[6];
            #pragma unroll
            for (int i = 0; i < 3; ++i) {
                const float2 v = *(const float2*)(xp + 2 * i);
                a[2 * i] = v.x; a[2 * i + 1] = v.y;
            }
            #pragma unroll
            for (int kw = 0; kw < 3; ++kw) {
                const float4 w4 = *(const float4*)(w3t + (size_t)(kh * 3 + kw) * 2304 + oh * 48 + ow0);
                acc[0] = fmaf(a[kw    ], w4.x, acc[0]);
                acc[1] = fmaf(a[kw + 1], w4.y, acc[1]);
                acc[2] = fmaf(a[kw + 2], w4.z, acc[2]);
                acc[3] = fmaf(a[kw + 3], w4.w, acc[3]);
            }
        }
        float4 st;
        #pragma unroll
        for (int o = 0; o < 4; ++o) {
            const float v = fmaxf(acc[o], 0.f);
            (&st.x)[o] = v; ls += v; lq = fmaf(v, v, lq);
        }
        *(float4*)(y48 + oh * 48 + ow0) = st;
    }
    const float2 s3 = bstats(ls, lq, 1.f / 2304.f, red, t);

    // ---- LN3 + pool -> xs24 ----
    if (t < 576) {
        const int ph = t / 24, pw = t - ph * 24;
        const int r0 = 2 * ph, c0 = 2 * pw;
        const float2 u0 = *(const float2*)(y48 + r0 * 48 + c0);
        const float2 u1 = *(const float2*)(y48 + (r0 + 1) * 48 + c0);
        const int i00 = r0 * 48 + c0, i10 = i00 + 48;
        const float v0 = (u0.x - s3.x) * s3.y * g3[i00]     + be3[i00];
        const float v1 = (u0.y - s3.x) * s3.y * g3[i00 + 1] + be3[i00 + 1];
        const float v2 = (u1.x - s3.x) * s3.y * g3[i10]     + be3[i10];
        const float v3 = (u1.y - s3.x) * s3.y * g3[i10 + 1] + be3[i10 + 1];
        xs24[ph * 24 + pw] = fmaxf(fmaxf(v0, v1), fmaxf(v2, v3));
    }
    __syncthreads();

    // ---- L4: 24 -> conv3 -> relu -> y22 ----
    ls = 0.f; lq = 0.f;
    if (t < 132) {
        const int oh = t / 6, qc = t - oh * 6;
        const int ow0 = qc * 4;
        float acc[4];
        #pragma unroll
        for (int o = 0; o < 4; ++o) acc[o] = (ow0 + o < 22) ? b4[oh * 22 + ow0 + o] : 0.f;
        #pragma unroll
        for (int kh = 0; kh < 3; ++kh) {
            const float* xp = xs24 + (oh + kh) * 24 + ow0;
            float a[6];
            #pragma unroll
            for (int i = 0; i < 3; ++i) {
                const float2 v = *(const float2*)(xp + 2 * i);
                a[2 * i] = v.x; a[2 * i + 1] = v.y;
            }
            #pragma unroll
            for (int kw = 0; kw < 3; ++kw) {
                const float4 w4 = *(const float4*)(w4t + ((size_t)(kh * 3 + kw) * 22 + oh) * 24 + ow0);
                acc[0] = fmaf(a[kw    ], w4.x, acc[0]);
                acc[1] = fmaf(a[kw + 1], w4.y, acc[1]);
                acc[2] = fmaf(a[kw + 2], w4.z, acc[2]);
                acc[3] = fmaf(a[kw + 3], w4.w, acc[3]);
            }
        }
        #pragma unroll
        for (int o = 0; o < 4; ++o) {
            const float v = fmaxf(acc[o], 0.f);
            y22[oh * 24 + ow0 + o] = v;
            if (ow0 + o < 22) { ls += v; lq = fmaf(v, v, lq); }
        }
    }
    const float2 s4 = bstats(ls, lq, 1.f / 484.f, red, t);

    // ---- LN4 in place ----
    if (t < 484) {
        const int oh = t / 22, ow = t - oh * 22;
        const int p = oh * 24 + ow;
        y22[p] = (y22[p] - s4.x) * s4.y * g4[t] + be4[t];
    }
    __syncthreads();

    // ---- L5: 22 -> conv3 -> relu -> y20 ----
    ls = 0.f; lq = 0.f;
    if (t < 100) {
        const int oh = t / 5, qc = t - oh * 5;
        const int ow0 = qc * 4;
        float acc[4];
        #pragma unroll
        for (int o = 0; o < 4; ++o) acc[o] = b5[oh * 20 + ow0 + o];
        #pragma unroll
        for (int kh = 0; kh < 3; ++kh) {
            const float* xp = y22 + (oh + kh) * 24 + ow0;
            float a[6];
            #pragma unroll
            for (int i = 0; i < 3; ++i) {
                const float2 v = *(const float2*)(xp + 2 * i);
                a[2 * i] = v.x; a[2 * i + 1] = v.y;
            }
            #pragma unroll
            for (int kw = 0; kw < 3; ++kw) {
                const float4 w4 = *(const float4*)(w5t + (size_t)(kh * 3 + kw) * 400 + oh * 20 + ow0);
                acc[0] = fmaf(a[kw    ], w4.x, acc[0]);
                acc[1] = fmaf(a[kw + 1], w4.y, acc[1]);
                acc[2] = fmaf(a[kw + 2], w4.z, acc[2]);
                acc[3] = fmaf(a[kw + 3], w4.w, acc[3]);
            }
        }
        #pragma unroll
        for (int o = 0; o < 4; ++o) {
            const float v = fmaxf(acc[o], 0.f);
            y20[oh * 20 + ow0 + o] = v;
            ls += v; lq = fmaf(v, v, lq);
        }
    }
    const float2 s5 = bstats(ls, lq, 1.f / 400.f, red, t);

    // ---- LN5 + pool -> xs10 ----
    if (t < 100) {
        const int ph = t / 10, pw = t - ph * 10;
        const int r0 = 2 * ph, c0 = 2 * pw;
        const float2 u0 = *(const float2*)(y20 + r0 * 20 + c0);
        const float2 u1 = *(const float2*)(y20 + (r0 + 1) * 20 + c0);
        const int i00 = r0 * 20 + c0, i10 = i00 + 20;
        const float v0 = (u0.x - s5.x) * s5.y * g5[i00]     + be5[i00];
        const float v1 = (u0.y - s5.x) * s5.y * g5[i00 + 1] + be5[i00 + 1];
        const float v2 = (u1.x - s5.x) * s5.y * g5[i10]     + be5[i10];
        const float v3 = (u1.y - s5.x) * s5.y * g5[i10 + 1] + be5[i10 + 1];
        xs10[ph * 10 + pw] = fmaxf(fmaxf(v0, v1), fmaxf(v2, v3));
    }
    __syncthreads();

    // ---- L6: 10 -> conv3 -> relu -> y8 ----
    ls = 0.f; lq = 0.f;
    if (t < 16) {
        const int oh = t / 2, qc = t - oh * 2;
        const int ow0 = qc * 4;
        float acc[4];
        #pragma unroll
        for (int o = 0; o < 4; ++o) acc[o] = b6[oh * 8 + ow0 + o];
        #pragma unroll
        for (int kh = 0; kh < 3; ++kh) {
            const float* xp = xs10 + (oh + kh) * 10 + ow0;
            float a[6];
            #pragma unroll
            for (int i = 0; i < 3; ++i) {
                const float2 v = *(const float2*)(xp + 2 * i);
                a[2 * i] = v.x; a[2 * i + 1] = v.y;
            }
            #pragma unroll
            for (int kw = 0; kw < 3; ++kw) {
                const float4 w4 = *(const float4*)(w6t + (size_t)(kh * 3 + kw) * 64 + oh * 8 + ow0);
                acc[0] = fmaf(a[kw    ], w4.x, acc[0]);
                acc[1] = fmaf(a[kw + 1], w4.y, acc[1]);
                acc[2] = fmaf(a[kw + 2], w4.z, acc[2]);
                acc[3] = fmaf(a[kw + 3], w4.w, acc[3]);
            }
        }
        #pragma unroll
        for (int o = 0; o < 4; ++o) {
            const float v = fmaxf(acc[o], 0.f);
            y8[oh * 8 + ow0 + o] = v;
            ls += v; lq = fmaf(v, v, lq);
        }
    }
    const float2 s6 = bstats(ls, lq, 1.f / 64.f, red, t);

    // ---- LN6 -> h ----
    if (t < 64) h[t] = (y8[t] - s6.x) * s6.y * g6[t] + be6[t];
    __syncthreads();

    // ---- FC 64 -> 1000 (1 task/thread) + softmax ----
    float lj = -INFINITY;
    if (t < 1000) {
        const float4* wr = (const float4*)(fcw + (size_t)t * 64);
        float acc = fcb[t];
        #pragma unroll
        for (int k = 0; k < 16; ++k) {
            const float4 w4 = wr[k];
            acc = fmaf(h[4 * k], w4.x,
                  fmaf(h[4 * k + 1], w4.y,
                  fmaf(h[4 * k + 2], w4.z,
                  fmaf(h[4 * k + 3], w4.w, acc))));
        }
        lj = acc;
    }
    float mx = lj;
    #pragma unroll
    for (int off = 32; off > 0; off >>= 1) mx = fmaxf(mx, __shfl_down(mx, off, 64));
    if (lane == 0) red[t >> 6][0] = mx;
    __syncthreads();
    float gmax = red[0][0];
    #pragma unroll
    for (int w = 1; w < 16; ++w) gmax = fmaxf(gmax, red[w][0]);

    const float e = (t < 1000) ? __expf(lj - gmax) : 0.f;
    float ssum = e;
    #pragma unroll
    for (int off = 32; off > 0; off >>= 1) ssum += __shfl_down(ssum, off, 64);
    if (lane == 0) red[t >> 6][1] = ssum;
    __syncthreads();
    float tot = 0.f;
    #pragma unroll
    for (int w = 0; w < 16; ++w) tot += red[w][1];
    if (t < 1000) out[(size_t)b * 1000 + t] = e / tot;
}

extern "C" void kernel_launch(void* const* d_in, const int* in_sizes, int n_in,
                              void* d_out, int out_size, void* d_ws, size_t ws_size,
                              hipStream_t stream) {
    const float* x   = (const float*)d_in[0];
    const float* w1  = (const float*)d_in[1];
    const float* b1  = (const float*)d_in[2];
    const float* g1  = (const float*)d_in[3];
    const float* be1 = (const float*)d_in[4];
    const float* w2  = (const float*)d_in[5];
    const float* b2  = (const float*)d_in[6];
    const float* g2  = (const float*)d_in[7];
    const float* be2 = (const float*)d_in[8];
    const float* w3  = (const float*)d_in[9];
    const float* b3  = (const float*)d_in[10];
    const float* g3  = (const float*)d_in[11];
    const float* be3 = (const float*)d_in[12];
    const float* w4  = (const float*)d_in[13];
    const float* b4  = (const float*)d_in[14];
    const float* g4  = (const float*)d_in[15];
    const float* be4 = (const float*)d_in[16];
    const float* w5  = (const float*)d_in[17];
    const float* b5  = (const float*)d_in[18];
    const float* g5  = (const float*)d_in[19];
    const float* be5 = (const float*)d_in[20];
    const float* w6  = (const float*)d_in[21];
    const float* b6  = (const float*)d_in[22];
    const float* g6  = (const float*)d_in[23];
    const float* be6 = (const float*)d_in[24];
    const float* fcw = (const float*)d_in[25];
    const float* fcb = (const float*)d_in[26];

    float* xt   = (float*)d_ws;                 // 50176*128  = 6,422,528
    float* y1p  = xt   + 6422528;               // 128*109*112= 1,562,624
    float* w1pp = y1p  + 1562624;               // 11881*56   =   665,336
    float* w2t  = w1pp + 665336;                // 25*50*52   =    65,000
    float* w3t  = w2t  + 65000;                 // 9*2304     =    20,736
    float* w4t  = w3t  + 20736;                 // 9*22*24    =     4,752
    float* w5t  = w4t  + 4752;                  // 9*400      =     3,600
    float* w6t  = w5t  + 3600;                  // 9*64       =       576
    float* part = w6t  + 576;                   // 128*196*2  =    50,176
    float* g1pp = part + 50176;                 // 2916*4     =    11,664
    float* be1pp= g1pp + 11664;                 // 2916*4     =    11,664

    xpose<<<896, 256, 0, stream>>>(x, xt, w1,
                                   w2, w3, w4, w5, w6, g1, be1,
                                   w1pp, w2t, w3t, w4t, w5t, w6t,
                                   (float4*)g1pp, (float4*)be1pp);

    conv1<<<dim3(7, 28, 2), 256, 0, stream>>>(xt, w1pp, b1, y1p, part);

    tail<<<128, 1024, 0, stream>>>(y1p, part,
                                   (const float4*)g1pp, (const float4*)be1pp,
                                   w2t, b2, g2, be2,
                                   w3t, b3, g3, be3,
                                   w4t, b4, g4, be4,
                                   w5t, b5, g5, be5,
                                   w6t, b6, g6, be6,
                                   fcw, fcb, (float*)d_out);
}